// Round 3
// baseline (2721.186 us; speedup 1.0000x reference)
//
#include <hip/hip_runtime.h>
#include <math.h>

#define Bb 16
#define Nn 500
#define NT 501
#define Pp 100
#define Ee 128
#define Hh 8
#define Dd 16
#define Ff 512
#define Ll 6
#define Mtok (Bb*NT)   // 8016
#define PR (Bb*Pp)     // 1600

// ---------------------------------------------------------------- embed
__global__ __launch_bounds__(256) void embed_k(
    const float* __restrict__ depot_xy, const float* __restrict__ node_xy,
    const float* __restrict__ node_demand,
    const float* __restrict__ wD, const float* __restrict__ bD,
    const float* __restrict__ wN, const float* __restrict__ bN,
    float* __restrict__ x)
{
  int t = blockIdx.x*256 + threadIdx.x;
  if (t >= Mtok*Ee) return;
  int e   = t & (Ee-1);
  int tok = t >> 7;
  int b   = tok / NT;
  int n   = tok - b*NT;
  float v;
  if (n == 0) {
    v = depot_xy[b*2+0]*wD[0*Ee+e] + depot_xy[b*2+1]*wD[1*Ee+e] + bD[e];
  } else {
    int nn = n - 1;
    float c0 = node_xy[(b*Nn + nn)*2 + 0];
    float c1 = node_xy[(b*Nn + nn)*2 + 1];
    float c2 = node_demand[b*Nn + nn];
    v = c0*wN[0*Ee+e] + c1*wN[1*Ee+e] + c2*wN[2*Ee+e] + bN[e];
  }
  x[(size_t)tok*Ee + e] = v;
}

// ---------------------------------------------------------------- GEMM
// C[M,N] = A[M,K] @ W[K,N]  (+bias) (relu) (+res).  N%64==0, K%16==0.
__global__ __launch_bounds__(256) void gemm_k(
    const float* __restrict__ A, const float* __restrict__ W,
    const float* __restrict__ bias, const float* __restrict__ res,
    float* __restrict__ C, int M, int N, int K, int relu)
{
  __shared__ __align__(16) float As[16][64];
  __shared__ __align__(16) float Bs[16][64];
  int tid = threadIdx.x;
  int tx = tid & 15, ty = tid >> 4;
  int m0 = blockIdx.x * 64, n0 = blockIdx.y * 64;
  float acc[4][4];
  #pragma unroll
  for (int i=0;i<4;i++)
    #pragma unroll
    for (int j=0;j<4;j++) acc[i][j] = 0.f;

  int ar = tid >> 2;          // 0..63  A row in tile
  int ak = (tid & 3) << 2;    // 0,4,8,12
  int br = tid >> 4;          // 0..15  W row in tile
  int bc = (tid & 15) << 2;   // 0..60

  for (int k0 = 0; k0 < K; k0 += 16) {
    float4 av;
    if (m0 + ar < M) av = *(const float4*)(A + (size_t)(m0 + ar)*K + k0 + ak);
    else             av = make_float4(0.f,0.f,0.f,0.f);
    As[ak+0][ar] = av.x; As[ak+1][ar] = av.y; As[ak+2][ar] = av.z; As[ak+3][ar] = av.w;
    *(float4*)(&Bs[br][bc]) = *(const float4*)(W + (size_t)(k0 + br)*N + n0 + bc);
    __syncthreads();
    #pragma unroll
    for (int k=0;k<16;k++){
      float4 a4 = *(const float4*)(&As[k][ty*4]);
      float4 b4 = *(const float4*)(&Bs[k][tx*4]);
      float avv[4] = {a4.x,a4.y,a4.z,a4.w};
      float bvv[4] = {b4.x,b4.y,b4.z,b4.w};
      #pragma unroll
      for (int i=0;i<4;i++)
        #pragma unroll
        for (int j=0;j<4;j++)
          acc[i][j] = fmaf(avv[i], bvv[j], acc[i][j]);
    }
    __syncthreads();
  }

  float4 bv = make_float4(0.f,0.f,0.f,0.f);
  if (bias) bv = *(const float4*)(bias + n0 + tx*4);
  #pragma unroll
  for (int i=0;i<4;i++){
    int row = m0 + ty*4 + i;
    if (row >= M) continue;
    float4 o;
    o.x = acc[i][0] + bv.x; o.y = acc[i][1] + bv.y;
    o.z = acc[i][2] + bv.z; o.w = acc[i][3] + bv.w;
    if (relu){ o.x=fmaxf(o.x,0.f); o.y=fmaxf(o.y,0.f); o.z=fmaxf(o.z,0.f); o.w=fmaxf(o.w,0.f); }
    if (res){
      float4 rv = *(const float4*)(res + (size_t)row*N + n0 + tx*4);
      o.x += rv.x; o.y += rv.y; o.z += rv.z; o.w += rv.w;
    }
    *(float4*)(C + (size_t)row*N + n0 + tx*4) = o;
  }
}

// ---------------------------------------------------------------- attention
__device__ __forceinline__ float dot4(float4 a, float4 b){
  return fmaf(a.x,b.x, fmaf(a.y,b.y, fmaf(a.z,b.z, a.w*b.w)));
}

// encoder self-attention: one (b,h,chunk) per block, one query per thread.
__global__ __launch_bounds__(256) void attn_enc_k(
    const float* __restrict__ Q, const float* __restrict__ Kv,
    const float* __restrict__ Vv, float* __restrict__ O)
{
  int blk = blockIdx.x;            // ((b*H)+h)*2 + c
  int c  = blk & 1;
  int bh = blk >> 1;
  int h  = bh & (Hh-1);
  int b  = bh >> 3;
  int p  = c*256 + (int)threadIdx.x;
  if (p >= NT) return;
  const size_t base = ((size_t)b*NT)*Ee + h*Dd;
  const float4* qp = (const float4*)(Q + base + (size_t)p*Ee);
  float4 q0=qp[0], q1=qp[1], q2=qp[2], q3=qp[3];
  float m = -1e30f, l = 0.f;
  float4 o0=make_float4(0,0,0,0), o1=o0, o2=o0, o3=o0;
  #pragma unroll 2
  for (int j=0;j<NT;++j){
    const float4* kp = (const float4*)(Kv + base + (size_t)j*Ee);
    float4 k0=kp[0],k1=kp[1],k2=kp[2],k3=kp[3];
    float s = (dot4(q0,k0)+dot4(q1,k1)) + (dot4(q2,k2)+dot4(q3,k3));
    s *= 0.25f;
    float mn = fmaxf(m, s);
    float cf = expf(m - mn);
    float w  = expf(s - mn);
    l = l*cf + w;
    const float4* vp = (const float4*)(Vv + base + (size_t)j*Ee);
    float4 v0=vp[0],v1=vp[1],v2=vp[2],v3=vp[3];
    o0.x=fmaf(w,v0.x,o0.x*cf); o0.y=fmaf(w,v0.y,o0.y*cf); o0.z=fmaf(w,v0.z,o0.z*cf); o0.w=fmaf(w,v0.w,o0.w*cf);
    o1.x=fmaf(w,v1.x,o1.x*cf); o1.y=fmaf(w,v1.y,o1.y*cf); o1.z=fmaf(w,v1.z,o1.z*cf); o1.w=fmaf(w,v1.w,o1.w*cf);
    o2.x=fmaf(w,v2.x,o2.x*cf); o2.y=fmaf(w,v2.y,o2.y*cf); o2.z=fmaf(w,v2.z,o2.z*cf); o2.w=fmaf(w,v2.w,o2.w*cf);
    o3.x=fmaf(w,v3.x,o3.x*cf); o3.y=fmaf(w,v3.y,o3.y*cf); o3.z=fmaf(w,v3.z,o3.z*cf); o3.w=fmaf(w,v3.w,o3.w*cf);
    m = mn;
  }
  float inv = 1.0f/l;
  float4* op = (float4*)(O + base + (size_t)p*Ee);
  op[0] = make_float4(o0.x*inv,o0.y*inv,o0.z*inv,o0.w*inv);
  op[1] = make_float4(o1.x*inv,o1.y*inv,o1.z*inv,o1.w*inv);
  op[2] = make_float4(o2.x*inv,o2.y*inv,o2.z*inv,o2.w*inv);
  op[3] = make_float4(o3.x*inv,o3.y*inv,o3.z*inv,o3.w*inv);
}

// decoder cross-attention with additive mask — f64 accumulation
__global__ __launch_bounds__(128) void attn_dec_k(
    const float* __restrict__ Q, const float* __restrict__ Kv,
    const float* __restrict__ Vv, const float* __restrict__ mask,
    float* __restrict__ O)
{
  int bh = blockIdx.x;
  int h  = bh & (Hh-1);
  int b  = bh >> 3;
  int p  = threadIdx.x;
  if (p >= Pp) return;
  const float* qp = Q + ((size_t)(b*Pp + p))*Ee + h*Dd;
  double q[16];
  #pragma unroll
  for (int i=0;i<16;i++) q[i] = (double)qp[i];
  const size_t kbase = ((size_t)b*NT)*Ee + h*Dd;
  const float* mrow = mask + ((size_t)(b*Pp + p))*NT;
  double m = -1e300, l = 0.0;
  double o[16];
  #pragma unroll
  for (int i=0;i<16;i++) o[i] = 0.0;
  for (int j=0;j<NT;++j){
    const float* kp = Kv + kbase + (size_t)j*Ee;
    double s = 0.0;
    #pragma unroll
    for (int i=0;i<16;i++) s = fma(q[i], (double)kp[i], s);
    s = s*0.25 + (double)mrow[j];
    double mn = fmax(m, s);
    double cf = exp(m - mn);
    double w  = exp(s - mn);
    l = l*cf + w;
    const float* vp = Vv + kbase + (size_t)j*Ee;
    #pragma unroll
    for (int i=0;i<16;i++) o[i] = fma(w, (double)vp[i], o[i]*cf);
    m = mn;
  }
  double inv = 1.0/l;
  float* op = O + ((size_t)(b*Pp + p))*Ee + h*Dd;
  #pragma unroll
  for (int i=0;i<16;i++) op[i] = (float)(o[i]*inv);
}

// ---------------------------------------------------------------- decoder small ops
__global__ __launch_bounds__(256) void gather_k(
    const float* __restrict__ x, const int* __restrict__ cur, float* __restrict__ encl)
{
  int t = blockIdx.x*256 + threadIdx.x;
  if (t >= PR*Ee) return;
  int e = t & (Ee-1);
  int r = t >> 7;            // b*P + p
  int b = r / Pp;
  int node = cur[r];
  encl[(size_t)r*Ee + e] = x[((size_t)(b*NT + node))*Ee + e];
}

// q = concat(encl, load) @ Wq[129,128]  (f64 accum)
__global__ __launch_bounds__(128) void decq_k(
    const float* __restrict__ encl, const float* __restrict__ loadv,
    const float* __restrict__ Wq, float* __restrict__ q)
{
  __shared__ float row[Ee];
  int r = blockIdx.x, e = threadIdx.x;
  row[e] = encl[(size_t)r*Ee + e];
  __syncthreads();
  double acc = 0.0;
  for (int k=0;k<Ee;k++) acc = fma((double)row[k], (double)Wq[k*128 + e], acc);
  acc = fma((double)loadv[r], (double)Wq[Ee*128 + e], acc);
  q[(size_t)r*128 + e] = (float)acc;
}

// mh = att@W + b + encl + load*capw  (f64 accum)
__global__ __launch_bounds__(128) void dec_comb_k(
    const float* __restrict__ att, const float* __restrict__ W,
    const float* __restrict__ bias, const float* __restrict__ encl,
    const float* __restrict__ loadv, const float* __restrict__ capw,
    float* __restrict__ mh)
{
  __shared__ float row[Ee];
  int r = blockIdx.x, e = threadIdx.x;
  row[e] = att[(size_t)r*Ee + e];
  __syncthreads();
  double acc = 0.0;
  for (int k=0;k<Ee;k++) acc = fma((double)row[k], (double)W[k*Ee + e], acc);
  mh[(size_t)r*Ee + e] = (float)(acc + (double)bias[e] + (double)encl[(size_t)r*Ee + e]
                                 + (double)loadv[r]*(double)capw[e]);
}

// score[b,p,n] = dot(qref[b,p], x[b,n]) / sqrt(E)  (f64 accum)
__global__ __launch_bounds__(128) void score_k(
    const float* __restrict__ qref, const float* __restrict__ x, float* __restrict__ score)
{
  __shared__ float q[Ee];
  int r = blockIdx.x;
  int b = r / Pp;
  q[threadIdx.x] = qref[(size_t)r*Ee + threadIdx.x];
  __syncthreads();
  for (int n = threadIdx.x; n < NT; n += 128){
    const float* xr = x + ((size_t)(b*NT + n))*Ee;
    double acc = 0.0;
    #pragma unroll 4
    for (int k=0;k<Ee;k++) acc = fma((double)q[k], (double)xr[k], acc);
    score[(size_t)r*NT + n] = (float)(acc * 0.08838834764831843);  // 1/sqrt(128)
  }
}

// ---------------------------------------------------------------- threefry noise
// jax >= 0.4.30 default: jax_threefry_partitionable=True.
// Per element i: threefry2x32(key=(0,42), x=(hi(i), lo(i))=(0, i)), bits = out0 ^ out1.
__device__ __forceinline__ unsigned rotl32(unsigned x, int r){ return (x<<r)|(x>>(32-r)); }

__device__ float tf_normal(unsigned idx)
{
  unsigned x0 = 0u;      // counts >> 32
  unsigned x1 = idx;     // counts & 0xffffffff
  const unsigned ks[3] = {0u, 42u, 0u ^ 42u ^ 0x1BD11BDAu};
  x0 += ks[0]; x1 += ks[1];
  const int rotA[4] = {13,15,26,6};
  const int rotB[4] = {17,29,16,24};
  #pragma unroll
  for (int i=0;i<5;i++){
    #pragma unroll
    for (int q=0;q<4;q++){
      int rr = (i&1) ? rotB[q] : rotA[q];
      x0 += x1; x1 = rotl32(x1, rr); x1 ^= x0;
    }
    x0 += ks[(i+1)%3];
    x1 += ks[(i+2)%3] + (unsigned)(i+1);
  }
  unsigned bits = x0 ^ x1;   // partitionable 32-bit draw
  // uniform in [lo, 1): jax _uniform  (f32, bit-matching jax)
  float f = __uint_as_float((bits >> 9) | 0x3f800000u) - 1.0f;
  const float lo = -0.99999994f;               // nextafter(-1,0) f32
  float u = f * 2.0f + lo;                     // (hi-lo) rounds to 2.0f in f32
  u = fmaxf(lo, u);
  // erfinv (XLA f32)
  float w = -log1pf(-u*u);
  float p;
  if (w < 5.0f) {
    w -= 2.5f;
    p = 2.81022636e-08f;
    p = fmaf(p, w, 3.43273939e-07f);
    p = fmaf(p, w, -3.5233877e-06f);
    p = fmaf(p, w, -4.39150654e-06f);
    p = fmaf(p, w, 0.00021858087f);
    p = fmaf(p, w, -0.00125372503f);
    p = fmaf(p, w, -0.00417768164f);
    p = fmaf(p, w, 0.246640727f);
    p = fmaf(p, w, 1.50140941f);
  } else {
    w = sqrtf(w) - 3.0f;
    p = -0.000200214257f;
    p = fmaf(p, w, 0.000100950558f);
    p = fmaf(p, w, 0.00134934322f);
    p = fmaf(p, w, -0.00367342844f);
    p = fmaf(p, w, 0.00573950773f);
    p = fmaf(p, w, -0.0076224613f);
    p = fmaf(p, w, 0.00943887047f);
    p = fmaf(p, w, 1.00167406f);
    p = fmaf(p, w, 2.83297682f);
  }
  return 1.4142135623730951f * (p * u);   // sqrt(2) * erfinv(u)
}

// ---------------------------------------------------------------- finalize (f64)
__global__ __launch_bounds__(512) void final_k(
    const float* __restrict__ score, const float* __restrict__ cur_dist,
    const float* __restrict__ ninf, float* __restrict__ out)
{
  __shared__ double red[512];
  const double NM = 50.0/501.0;
  const double C1 = 1.0 - 50.0/501.0;
  int r = blockIdx.x;
  int t = threadIdx.x;
  double cd = 0.0, dmn = 1e300, dmx = -1e300;
  if (t < NT) { cd = (double)cur_dist[(size_t)r*NT + t]; dmn = cd; dmx = cd; }
  red[t] = dmn; __syncthreads();
  for (int s=256;s>0;s>>=1){ if (t<s) red[t]=fmin(red[t],red[t+s]); __syncthreads(); }
  double dmin = red[0]; __syncthreads();
  red[t] = dmx; __syncthreads();
  for (int s=256;s>0;s>>=1){ if (t<s) red[t]=fmax(red[t],red[t+s]); __syncthreads(); }
  double dmax = red[0]; __syncthreads();

  double sval = -1e300;
  if (t < NT) {
    double nd = (cd - dmin) / (dmax - dmin + 1e-6);
    double z  = (double)tf_normal((unsigned)r*501u + (unsigned)t);
    double s  = (double)score[(size_t)r*NT + t] - C1*log(nd + 1e-6) + (z*0.2 + 0.5)*NM;
    sval = 10.0*tanh(s) + (double)ninf[(size_t)r*NT + t];
  }
  red[t] = sval; __syncthreads();
  for (int s=256;s>0;s>>=1){ if (t<s) red[t]=fmax(red[t],red[t+s]); __syncthreads(); }
  double smax = red[0]; __syncthreads();
  double e = (t < NT) ? exp(sval - smax) : 0.0;
  red[t] = e; __syncthreads();
  for (int s=256;s>0;s>>=1){ if (t<s) red[t]+=red[t+s]; __syncthreads(); }
  double ssum = red[0];
  if (t < NT) out[(size_t)r*NT + t] = (float)(e / ssum);
}

// ---------------------------------------------------------------- launch
extern "C" void kernel_launch(void* const* d_in, const int* in_sizes, int n_in,
                              void* d_out, int out_size, void* d_ws, size_t ws_size,
                              hipStream_t stream)
{
  (void)in_sizes; (void)n_in; (void)out_size; (void)ws_size;
  const float* depot_xy    = (const float*)d_in[0];
  const float* node_xy     = (const float*)d_in[1];
  const float* node_demand = (const float*)d_in[2];
  const float* loadv       = (const float*)d_in[3];
  const float* cur_dist    = (const float*)d_in[4];
  const float* ninf        = (const float*)d_in[5];
  const int*   cur_node    = (const int*)d_in[6];
  const float* emb_depot_w = (const float*)d_in[7];
  const float* emb_depot_b = (const float*)d_in[8];
  const float* emb_node_w  = (const float*)d_in[9];
  const float* emb_node_b  = (const float*)d_in[10];
  const float* enc_wq      = (const float*)d_in[11];
  const float* enc_wk      = (const float*)d_in[12];
  const float* enc_wv      = (const float*)d_in[13];
  const float* enc_comb_w  = (const float*)d_in[14];
  const float* enc_comb_b  = (const float*)d_in[15];
  const float* enc_ff1_w   = (const float*)d_in[16];
  const float* enc_ff1_b   = (const float*)d_in[17];
  const float* enc_ff2_w   = (const float*)d_in[18];
  const float* enc_ff2_b   = (const float*)d_in[19];
  const float* dec_wq_last = (const float*)d_in[20];
  const float* dec_wk      = (const float*)d_in[21];
  const float* dec_wv      = (const float*)d_in[22];
  const float* dec_comb_w  = (const float*)d_in[23];
  const float* dec_comb_b  = (const float*)d_in[24];
  const float* dec_cap_w   = (const float*)d_in[25];
  const float* dec_ff1_w   = (const float*)d_in[26];
  const float* dec_ff1_b   = (const float*)d_in[27];
  const float* dec_ff2_w   = (const float*)d_in[28];
  const float* dec_ff2_b   = (const float*)d_in[29];

  float* ws = (float*)d_ws;
  const size_t SZ = (size_t)Mtok*Ee;   // 1,026,048
  float* xb   = ws + 0*SZ;
  float* qb   = ws + 1*SZ;
  float* kb   = ws + 2*SZ;
  float* vb   = ws + 3*SZ;
  float* atb  = ws + 4*SZ;
  float* o1b  = ws + 5*SZ;
  float* ffb  = ws + 6*SZ;             // Mtok*Ff floats
  // decoder reuse
  float* dk    = qb;
  float* dv    = kb;
  float* encl  = vb;
  float* qdec  = vb + 204800;
  float* attd  = vb + 409600;
  float* mhb   = vb + 614400;
  float* qrefb = atb;
  float* ffh2  = ffb;
  float* scoreb= o1b;

  embed_k<<<(Mtok*Ee + 255)/256, 256, 0, stream>>>(
      depot_xy, node_xy, node_demand, emb_depot_w, emb_depot_b,
      emb_node_w, emb_node_b, xb);

  dim3 g128((Mtok + 63)/64, Ee/64);
  dim3 gff ((Mtok + 63)/64, Ff/64);
  for (int l = 0; l < Ll; ++l) {
    gemm_k<<<g128, 256, 0, stream>>>(xb, enc_wq + (size_t)l*Ee*Ee, nullptr, nullptr, qb, Mtok, Ee, Ee, 0);
    gemm_k<<<g128, 256, 0, stream>>>(xb, enc_wk + (size_t)l*Ee*Ee, nullptr, nullptr, kb, Mtok, Ee, Ee, 0);
    gemm_k<<<g128, 256, 0, stream>>>(xb, enc_wv + (size_t)l*Ee*Ee, nullptr, nullptr, vb, Mtok, Ee, Ee, 0);
    attn_enc_k<<<Bb*Hh*2, 256, 0, stream>>>(qb, kb, vb, atb);
    gemm_k<<<g128, 256, 0, stream>>>(atb, enc_comb_w + (size_t)l*Ee*Ee, enc_comb_b + l*Ee, xb, o1b, Mtok, Ee, Ee, 0);
    gemm_k<<<gff, 256, 0, stream>>>(o1b, enc_ff1_w + (size_t)l*Ee*Ff, enc_ff1_b + l*Ff, nullptr, ffb, Mtok, Ff, Ee, 1);
    gemm_k<<<g128, 256, 0, stream>>>(ffb, enc_ff2_w + (size_t)l*Ff*Ee, enc_ff2_b + l*Ee, o1b, xb, Mtok, Ee, Ff, 0);
  }

  // decoder
  gemm_k<<<g128, 256, 0, stream>>>(xb, dec_wk, nullptr, nullptr, dk, Mtok, Ee, Ee, 0);
  gemm_k<<<g128, 256, 0, stream>>>(xb, dec_wv, nullptr, nullptr, dv, Mtok, Ee, Ee, 0);
  gather_k<<<(PR*Ee + 255)/256, 256, 0, stream>>>(xb, cur_node, encl);
  decq_k<<<PR, 128, 0, stream>>>(encl, loadv, dec_wq_last, qdec);
  attn_dec_k<<<Bb*Hh, 128, 0, stream>>>(qdec, dk, dv, ninf, attd);
  dec_comb_k<<<PR, 128, 0, stream>>>(attd, dec_comb_w, dec_comb_b, encl, loadv, dec_cap_w, mhb);
  dim3 gd1((PR + 63)/64, Ff/64);
  gemm_k<<<gd1, 256, 0, stream>>>(mhb, dec_ff1_w, dec_ff1_b, nullptr, ffh2, PR, Ff, Ee, 1);
  dim3 gd2((PR + 63)/64, Ee/64);
  gemm_k<<<gd2, 256, 0, stream>>>(ffh2, dec_ff2_w, dec_ff2_b, mhb, qrefb, PR, Ee, Ff, 0);
  score_k<<<PR, 128, 0, stream>>>(qrefb, xb, scoreb);
  final_k<<<PR, 512, 0, stream>>>(scoreb, cur_dist, ninf, (float*)d_out);
}

// Round 4
// 2331.026 us; speedup vs baseline: 1.1674x; 1.1674x over previous
//
#include <hip/hip_runtime.h>
#include <math.h>

#define Bb 16
#define Nn 500
#define NT 501
#define Pp 100
#define Ee 128
#define Hh 8
#define Dd 16
#define Ff 512
#define Ll 6
#define Mtok (Bb*NT)   // 8016
#define PR (Bb*Pp)     // 1600

// ---------------------------------------------------------------- embed
__global__ __launch_bounds__(256) void embed_k(
    const float* __restrict__ depot_xy, const float* __restrict__ node_xy,
    const float* __restrict__ node_demand,
    const float* __restrict__ wD, const float* __restrict__ bD,
    const float* __restrict__ wN, const float* __restrict__ bN,
    float* __restrict__ x)
{
  int t = blockIdx.x*256 + threadIdx.x;
  if (t >= Mtok*Ee) return;
  int e   = t & (Ee-1);
  int tok = t >> 7;
  int b   = tok / NT;
  int n   = tok - b*NT;
  float v;
  if (n == 0) {
    v = depot_xy[b*2+0]*wD[0*Ee+e] + depot_xy[b*2+1]*wD[1*Ee+e] + bD[e];
  } else {
    int nn = n - 1;
    float c0 = node_xy[(b*Nn + nn)*2 + 0];
    float c1 = node_xy[(b*Nn + nn)*2 + 1];
    float c2 = node_demand[b*Nn + nn];
    v = c0*wN[0*Ee+e] + c1*wN[1*Ee+e] + c2*wN[2*Ee+e] + bN[e];
  }
  x[(size_t)tok*Ee + e] = v;
}

// ---------------------------------------------------------------- GEMM
// C[M,N] = A[M,K] @ W[K,N]  (+bias) (relu) (+res).  N%64==0, K%16==0.
// Software-pipelined: next K-tile's global loads issued before compute.
__global__ __launch_bounds__(256) void gemm_k(
    const float* __restrict__ A, const float* __restrict__ W,
    const float* __restrict__ bias, const float* __restrict__ res,
    float* __restrict__ C, int M, int N, int K, int relu)
{
  __shared__ __align__(16) float As[16][64];
  __shared__ __align__(16) float Bs[16][64];
  int tid = threadIdx.x;
  int tx = tid & 15, ty = tid >> 4;
  int m0 = blockIdx.x * 64, n0 = blockIdx.y * 64;
  float acc[4][4];
  #pragma unroll
  for (int i=0;i<4;i++)
    #pragma unroll
    for (int j=0;j<4;j++) acc[i][j] = 0.f;

  int ar = tid >> 2;          // 0..63  A row in tile
  int ak = (tid & 3) << 2;    // 0,4,8,12
  int br = tid >> 4;          // 0..15  W row in tile
  int bc = (tid & 15) << 2;   // 0..60

  const float* Ap = A + (size_t)(m0 + ar)*K + ak;
  const float* Wp = W + (size_t)br*N + n0 + bc;
  bool aok = (m0 + ar) < M;

  float4 av = aok ? *(const float4*)(Ap) : make_float4(0.f,0.f,0.f,0.f);
  float4 wv = *(const float4*)(Wp);

  for (int k0 = 0; k0 < K; k0 += 16) {
    As[ak+0][ar] = av.x; As[ak+1][ar] = av.y; As[ak+2][ar] = av.z; As[ak+3][ar] = av.w;
    *(float4*)(&Bs[br][bc]) = wv;
    __syncthreads();
    if (k0 + 16 < K) {
      av = aok ? *(const float4*)(Ap + k0 + 16) : make_float4(0.f,0.f,0.f,0.f);
      wv = *(const float4*)(Wp + (size_t)(k0 + 16)*N);
    }
    #pragma unroll
    for (int k=0;k<16;k++){
      float4 a4 = *(const float4*)(&As[k][ty*4]);
      float4 b4 = *(const float4*)(&Bs[k][tx*4]);
      float avv[4] = {a4.x,a4.y,a4.z,a4.w};
      float bvv[4] = {b4.x,b4.y,b4.z,b4.w};
      #pragma unroll
      for (int i=0;i<4;i++)
        #pragma unroll
        for (int j=0;j<4;j++)
          acc[i][j] = fmaf(avv[i], bvv[j], acc[i][j]);
    }
    __syncthreads();
  }

  float4 bv = make_float4(0.f,0.f,0.f,0.f);
  if (bias) bv = *(const float4*)(bias + n0 + tx*4);
  #pragma unroll
  for (int i=0;i<4;i++){
    int row = m0 + ty*4 + i;
    if (row >= M) continue;
    float4 o;
    o.x = acc[i][0] + bv.x; o.y = acc[i][1] + bv.y;
    o.z = acc[i][2] + bv.z; o.w = acc[i][3] + bv.w;
    if (relu){ o.x=fmaxf(o.x,0.f); o.y=fmaxf(o.y,0.f); o.z=fmaxf(o.z,0.f); o.w=fmaxf(o.w,0.f); }
    if (res){
      float4 rv = *(const float4*)(res + (size_t)row*N + n0 + tx*4);
      o.x += rv.x; o.y += rv.y; o.z += rv.z; o.w += rv.w;
    }
    *(float4*)(C + (size_t)row*N + n0 + tx*4) = o;
  }
}

// ---------------------------------------------------------------- attention
__device__ __forceinline__ float dot4(float4 a, float4 b){
  return fmaf(a.x,b.x, fmaf(a.y,b.y, fmaf(a.z,b.z, a.w*b.w)));
}

// encoder self-attention: one (b,h,chunk) per block, one query per thread.
__global__ __launch_bounds__(256) void attn_enc_k(
    const float* __restrict__ Q, const float* __restrict__ Kv,
    const float* __restrict__ Vv, float* __restrict__ O)
{
  int blk = blockIdx.x;            // ((b*H)+h)*2 + c
  int c  = blk & 1;
  int bh = blk >> 1;
  int h  = bh & (Hh-1);
  int b  = bh >> 3;
  int p  = c*256 + (int)threadIdx.x;
  if (p >= NT) return;
  const size_t base = ((size_t)b*NT)*Ee + h*Dd;
  const float4* qp = (const float4*)(Q + base + (size_t)p*Ee);
  float4 q0=qp[0], q1=qp[1], q2=qp[2], q3=qp[3];
  float m = -1e30f, l = 0.f;
  float4 o0=make_float4(0,0,0,0), o1=o0, o2=o0, o3=o0;
  #pragma unroll 2
  for (int j=0;j<NT;++j){
    const float4* kp = (const float4*)(Kv + base + (size_t)j*Ee);
    float4 k0=kp[0],k1=kp[1],k2=kp[2],k3=kp[3];
    float s = (dot4(q0,k0)+dot4(q1,k1)) + (dot4(q2,k2)+dot4(q3,k3));
    s *= 0.25f;
    float mn = fmaxf(m, s);
    float cf = __expf(m - mn);
    float w  = __expf(s - mn);
    l = l*cf + w;
    const float4* vp = (const float4*)(Vv + base + (size_t)j*Ee);
    float4 v0=vp[0],v1=vp[1],v2=vp[2],v3=vp[3];
    o0.x=fmaf(w,v0.x,o0.x*cf); o0.y=fmaf(w,v0.y,o0.y*cf); o0.z=fmaf(w,v0.z,o0.z*cf); o0.w=fmaf(w,v0.w,o0.w*cf);
    o1.x=fmaf(w,v1.x,o1.x*cf); o1.y=fmaf(w,v1.y,o1.y*cf); o1.z=fmaf(w,v1.z,o1.z*cf); o1.w=fmaf(w,v1.w,o1.w*cf);
    o2.x=fmaf(w,v2.x,o2.x*cf); o2.y=fmaf(w,v2.y,o2.y*cf); o2.z=fmaf(w,v2.z,o2.z*cf); o2.w=fmaf(w,v2.w,o2.w*cf);
    o3.x=fmaf(w,v3.x,o3.x*cf); o3.y=fmaf(w,v3.y,o3.y*cf); o3.z=fmaf(w,v3.z,o3.z*cf); o3.w=fmaf(w,v3.w,o3.w*cf);
    m = mn;
  }
  float inv = 1.0f/l;
  float4* op = (float4*)(O + base + (size_t)p*Ee);
  op[0] = make_float4(o0.x*inv,o0.y*inv,o0.z*inv,o0.w*inv);
  op[1] = make_float4(o1.x*inv,o1.y*inv,o1.z*inv,o1.w*inv);
  op[2] = make_float4(o2.x*inv,o2.y*inv,o2.z*inv,o2.w*inv);
  op[3] = make_float4(o3.x*inv,o3.y*inv,o3.z*inv,o3.w*inv);
}

// decoder cross-attention: one block per (b,p), 128 threads = (head h, dim i).
// Coalesced K/V loads; dot via shfl_xor reduce within 16-lane head groups.
__global__ __launch_bounds__(128) void attn_dec_k(
    const float* __restrict__ Q, const float* __restrict__ Kv,
    const float* __restrict__ Vv, const float* __restrict__ mask,
    float* __restrict__ O)
{
  int r = blockIdx.x;              // b*Pp + p
  int b = r / Pp;
  int t = threadIdx.x;             // h*16 + i
  float qv = Q[(size_t)r*Ee + t];
  const float* kb = Kv + ((size_t)b*NT)*Ee;
  const float* vb = Vv + ((size_t)b*NT)*Ee;
  const float* mrow = mask + (size_t)r*NT;
  float m = -1e30f, l = 0.f, o = 0.f;
  for (int j=0;j<NT;++j){
    float kv = kb[(size_t)j*Ee + t];
    float s = qv * kv;
    s += __shfl_xor(s, 1, 16);
    s += __shfl_xor(s, 2, 16);
    s += __shfl_xor(s, 4, 16);
    s += __shfl_xor(s, 8, 16);
    s = s*0.25f + mrow[j];
    float mn = fmaxf(m, s);
    float cf = __expf(m - mn);
    float w  = __expf(s - mn);
    l = l*cf + w;
    o = fmaf(w, vb[(size_t)j*Ee + t], o*cf);
    m = mn;
  }
  O[(size_t)r*Ee + t] = o / l;
}

// ---------------------------------------------------------------- decoder small ops
__global__ __launch_bounds__(256) void gather_k(
    const float* __restrict__ x, const int* __restrict__ cur, float* __restrict__ encl)
{
  int t = blockIdx.x*256 + threadIdx.x;
  if (t >= PR*Ee) return;
  int e = t & (Ee-1);
  int r = t >> 7;            // b*P + p
  int b = r / Pp;
  int node = cur[r];
  encl[(size_t)r*Ee + e] = x[((size_t)(b*NT + node))*Ee + e];
}

// q = concat(encl, load) @ Wq[129,128]
__global__ __launch_bounds__(128) void decq_k(
    const float* __restrict__ encl, const float* __restrict__ loadv,
    const float* __restrict__ Wq, float* __restrict__ q)
{
  __shared__ float row[Ee];
  int r = blockIdx.x, e = threadIdx.x;
  row[e] = encl[(size_t)r*Ee + e];
  __syncthreads();
  float acc = 0.f;
  #pragma unroll 4
  for (int k=0;k<Ee;k++) acc = fmaf(row[k], Wq[k*128 + e], acc);
  acc = fmaf(loadv[r], Wq[Ee*128 + e], acc);
  q[(size_t)r*128 + e] = acc;
}

// mh = att@W + b + encl + load*capw
__global__ __launch_bounds__(128) void dec_comb_k(
    const float* __restrict__ att, const float* __restrict__ W,
    const float* __restrict__ bias, const float* __restrict__ encl,
    const float* __restrict__ loadv, const float* __restrict__ capw,
    float* __restrict__ mh)
{
  __shared__ float row[Ee];
  int r = blockIdx.x, e = threadIdx.x;
  row[e] = att[(size_t)r*Ee + e];
  __syncthreads();
  float acc = 0.f;
  #pragma unroll 4
  for (int k=0;k<Ee;k++) acc = fmaf(row[k], W[k*Ee + e], acc);
  mh[(size_t)r*Ee + e] = acc + bias[e] + encl[(size_t)r*Ee + e] + loadv[r]*capw[e];
}

// score[b,p,n] = dot(qref[b,p], x[b,n]) / sqrt(E)
__global__ __launch_bounds__(128) void score_k(
    const float* __restrict__ qref, const float* __restrict__ x, float* __restrict__ score)
{
  __shared__ float q[Ee];
  int r = blockIdx.x;
  int b = r / Pp;
  q[threadIdx.x] = qref[(size_t)r*Ee + threadIdx.x];
  __syncthreads();
  for (int n = threadIdx.x; n < NT; n += 128){
    const float4* xr = (const float4*)(x + ((size_t)(b*NT + n))*Ee);
    float acc = 0.f;
    #pragma unroll
    for (int k=0;k<Ee/4;k++){
      float4 xv = xr[k];
      const float* qq = &q[k*4];
      acc = fmaf(qq[0],xv.x, fmaf(qq[1],xv.y, fmaf(qq[2],xv.z, fmaf(qq[3],xv.w, acc))));
    }
    score[(size_t)r*NT + n] = acc * 0.08838834764831845f;  // 1/sqrt(128)
  }
}

// ---------------------------------------------------------------- threefry noise
// jax >= 0.4.30 default: jax_threefry_partitionable=True.
// Per element i: threefry2x32(key=(0,42), x=(hi(i), lo(i))=(0, i)), bits = out0 ^ out1.
__device__ __forceinline__ unsigned rotl32(unsigned x, int r){ return (x<<r)|(x>>(32-r)); }

__device__ float tf_normal(unsigned idx)
{
  unsigned x0 = 0u;      // counts >> 32
  unsigned x1 = idx;     // counts & 0xffffffff
  const unsigned ks[3] = {0u, 42u, 0u ^ 42u ^ 0x1BD11BDAu};
  x0 += ks[0]; x1 += ks[1];
  const int rotA[4] = {13,15,26,6};
  const int rotB[4] = {17,29,16,24};
  #pragma unroll
  for (int i=0;i<5;i++){
    #pragma unroll
    for (int q=0;q<4;q++){
      int rr = (i&1) ? rotB[q] : rotA[q];
      x0 += x1; x1 = rotl32(x1, rr); x1 ^= x0;
    }
    x0 += ks[(i+1)%3];
    x1 += ks[(i+2)%3] + (unsigned)(i+1);
  }
  unsigned bits = x0 ^ x1;   // partitionable 32-bit draw
  // uniform in [lo, 1): jax _uniform  (f32, bit-matching jax)
  float f = __uint_as_float((bits >> 9) | 0x3f800000u) - 1.0f;
  const float lo = -0.99999994f;               // nextafter(-1,0) f32
  float u = f * 2.0f + lo;                     // (hi-lo) rounds to 2.0f in f32
  u = fmaxf(lo, u);
  // erfinv (XLA f32)
  float w = -log1pf(-u*u);
  float p;
  if (w < 5.0f) {
    w -= 2.5f;
    p = 2.81022636e-08f;
    p = fmaf(p, w, 3.43273939e-07f);
    p = fmaf(p, w, -3.5233877e-06f);
    p = fmaf(p, w, -4.39150654e-06f);
    p = fmaf(p, w, 0.00021858087f);
    p = fmaf(p, w, -0.00125372503f);
    p = fmaf(p, w, -0.00417768164f);
    p = fmaf(p, w, 0.246640727f);
    p = fmaf(p, w, 1.50140941f);
  } else {
    w = sqrtf(w) - 3.0f;
    p = -0.000200214257f;
    p = fmaf(p, w, 0.000100950558f);
    p = fmaf(p, w, 0.00134934322f);
    p = fmaf(p, w, -0.00367342844f);
    p = fmaf(p, w, 0.00573950773f);
    p = fmaf(p, w, -0.0076224613f);
    p = fmaf(p, w, 0.00943887047f);
    p = fmaf(p, w, 1.00167406f);
    p = fmaf(p, w, 2.83297682f);
  }
  return 1.4142135623730951f * (p * u);   // sqrt(2) * erfinv(u)
}

// ---------------------------------------------------------------- finalize (f32)
__global__ __launch_bounds__(512) void final_k(
    const float* __restrict__ score, const float* __restrict__ cur_dist,
    const float* __restrict__ ninf, float* __restrict__ out)
{
  __shared__ float red[512];
  const float NM = (float)(50.0/501.0);
  const float C1 = (float)(1.0 - 50.0/501.0);
  int r = blockIdx.x;
  int t = threadIdx.x;
  float cd = 0.f, dmn = 1e30f, dmx = -1e30f;
  if (t < NT) { cd = cur_dist[(size_t)r*NT + t]; dmn = cd; dmx = cd; }
  red[t] = dmn; __syncthreads();
  for (int s=256;s>0;s>>=1){ if (t<s) red[t]=fminf(red[t],red[t+s]); __syncthreads(); }
  float dmin = red[0]; __syncthreads();
  red[t] = dmx; __syncthreads();
  for (int s=256;s>0;s>>=1){ if (t<s) red[t]=fmaxf(red[t],red[t+s]); __syncthreads(); }
  float dmax = red[0]; __syncthreads();

  float sval = -1e30f;
  if (t < NT) {
    float nd = (cd - dmin) / (dmax - dmin + 1e-6f);
    float z  = tf_normal((unsigned)r*501u + (unsigned)t);
    float s  = score[(size_t)r*NT + t] - C1*logf(nd + 1e-6f) + (z*0.2f + 0.5f)*NM;
    sval = 10.0f*tanhf(s) + ninf[(size_t)r*NT + t];
  }
  red[t] = sval; __syncthreads();
  for (int s=256;s>0;s>>=1){ if (t<s) red[t]=fmaxf(red[t],red[t+s]); __syncthreads(); }
  float smax = red[0]; __syncthreads();
  float e = (t < NT) ? expf(sval - smax) : 0.f;
  red[t] = e; __syncthreads();
  for (int s=256;s>0;s>>=1){ if (t<s) red[t]+=red[t+s]; __syncthreads(); }
  float ssum = red[0];
  if (t < NT) out[(size_t)r*NT + t] = e / ssum;
}

// ---------------------------------------------------------------- launch
extern "C" void kernel_launch(void* const* d_in, const int* in_sizes, int n_in,
                              void* d_out, int out_size, void* d_ws, size_t ws_size,
                              hipStream_t stream)
{
  (void)in_sizes; (void)n_in; (void)out_size; (void)ws_size;
  const float* depot_xy    = (const float*)d_in[0];
  const float* node_xy     = (const float*)d_in[1];
  const float* node_demand = (const float*)d_in[2];
  const float* loadv       = (const float*)d_in[3];
  const float* cur_dist    = (const float*)d_in[4];
  const float* ninf        = (const float*)d_in[5];
  const int*   cur_node    = (const int*)d_in[6];
  const float* emb_depot_w = (const float*)d_in[7];
  const float* emb_depot_b = (const float*)d_in[8];
  const float* emb_node_w  = (const float*)d_in[9];
  const float* emb_node_b  = (const float*)d_in[10];
  const float* enc_wq      = (const float*)d_in[11];
  const float* enc_wk      = (const float*)d_in[12];
  const float* enc_wv      = (const float*)d_in[13];
  const float* enc_comb_w  = (const float*)d_in[14];
  const float* enc_comb_b  = (const float*)d_in[15];
  const float* enc_ff1_w   = (const float*)d_in[16];
  const float* enc_ff1_b   = (const float*)d_in[17];
  const float* enc_ff2_w   = (const float*)d_in[18];
  const float* enc_ff2_b   = (const float*)d_in[19];
  const float* dec_wq_last = (const float*)d_in[20];
  const float* dec_wk      = (const float*)d_in[21];
  const float* dec_wv      = (const float*)d_in[22];
  const float* dec_comb_w  = (const float*)d_in[23];
  const float* dec_comb_b  = (const float*)d_in[24];
  const float* dec_cap_w   = (const float*)d_in[25];
  const float* dec_ff1_w   = (const float*)d_in[26];
  const float* dec_ff1_b   = (const float*)d_in[27];
  const float* dec_ff2_w   = (const float*)d_in[28];
  const float* dec_ff2_b   = (const float*)d_in[29];

  float* ws = (float*)d_ws;
  const size_t SZ = (size_t)Mtok*Ee;   // 1,026,048
  float* xb   = ws + 0*SZ;
  float* qb   = ws + 1*SZ;
  float* kb   = ws + 2*SZ;
  float* vb   = ws + 3*SZ;
  float* atb  = ws + 4*SZ;
  float* o1b  = ws + 5*SZ;
  float* ffb  = ws + 6*SZ;             // Mtok*Ff floats
  // decoder reuse
  float* dk    = qb;
  float* dv    = kb;
  float* encl  = vb;
  float* qdec  = vb + 204800;
  float* attd  = vb + 409600;
  float* mhb   = vb + 614400;
  float* qrefb = atb;
  float* ffh2  = ffb;
  float* scoreb= o1b;

  embed_k<<<(Mtok*Ee + 255)/256, 256, 0, stream>>>(
      depot_xy, node_xy, node_demand, emb_depot_w, emb_depot_b,
      emb_node_w, emb_node_b, xb);

  dim3 g128((Mtok + 63)/64, Ee/64);
  dim3 gff ((Mtok + 63)/64, Ff/64);
  for (int l = 0; l < Ll; ++l) {
    gemm_k<<<g128, 256, 0, stream>>>(xb, enc_wq + (size_t)l*Ee*Ee, nullptr, nullptr, qb, Mtok, Ee, Ee, 0);
    gemm_k<<<g128, 256, 0, stream>>>(xb, enc_wk + (size_t)l*Ee*Ee, nullptr, nullptr, kb, Mtok, Ee, Ee, 0);
    gemm_k<<<g128, 256, 0, stream>>>(xb, enc_wv + (size_t)l*Ee*Ee, nullptr, nullptr, vb, Mtok, Ee, Ee, 0);
    attn_enc_k<<<Bb*Hh*2, 256, 0, stream>>>(qb, kb, vb, atb);
    gemm_k<<<g128, 256, 0, stream>>>(atb, enc_comb_w + (size_t)l*Ee*Ee, enc_comb_b + l*Ee, xb, o1b, Mtok, Ee, Ee, 0);
    gemm_k<<<gff, 256, 0, stream>>>(o1b, enc_ff1_w + (size_t)l*Ee*Ff, enc_ff1_b + l*Ff, nullptr, ffb, Mtok, Ff, Ee, 1);
    gemm_k<<<g128, 256, 0, stream>>>(ffb, enc_ff2_w + (size_t)l*Ff*Ee, enc_ff2_b + l*Ee, o1b, xb, Mtok, Ee, Ff, 0);
  }

  // decoder
  gemm_k<<<g128, 256, 0, stream>>>(xb, dec_wk, nullptr, nullptr, dk, Mtok, Ee, Ee, 0);
  gemm_k<<<g128, 256, 0, stream>>>(xb, dec_wv, nullptr, nullptr, dv, Mtok, Ee, Ee, 0);
  gather_k<<<(PR*Ee + 255)/256, 256, 0, stream>>>(xb, cur_node, encl);
  decq_k<<<PR, 128, 0, stream>>>(encl, loadv, dec_wq_last, qdec);
  attn_dec_k<<<PR, 128, 0, stream>>>(qdec, dk, dv, ninf, attd);
  dec_comb_k<<<PR, 128, 0, stream>>>(attd, dec_comb_w, dec_comb_b, encl, loadv, dec_cap_w, mhb);
  dim3 gd1((PR + 63)/64, Ff/64);
  gemm_k<<<gd1, 256, 0, stream>>>(mhb, dec_ff1_w, dec_ff1_b, nullptr, ffh2, PR, Ff, Ee, 1);
  dim3 gd2((PR + 63)/64, Ee/64);
  gemm_k<<<gd2, 256, 0, stream>>>(ffh2, dec_ff2_w, dec_ff2_b, mhb, qrefb, PR, Ee, Ff, 0);
  score_k<<<PR, 128, 0, stream>>>(qrefb, xb, scoreb);
  final_k<<<PR, 512, 0, stream>>>(scoreb, cur_dist, ninf, (float*)d_out);
}

// Round 5
// 1267.121 us; speedup vs baseline: 2.1475x; 1.8396x over previous
//
#include <hip/hip_runtime.h>
#include <math.h>

#define Bb 16
#define Nn 500
#define NT 501
#define Pp 100
#define Ee 128
#define Hh 8
#define Dd 16
#define Ff 512
#define Ll 6
#define Mtok (Bb*NT)   // 8016
#define PR (Bb*Pp)     // 1600
#define TJ 32          // attn_enc KV tile rows

// ---------------------------------------------------------------- embed
__global__ __launch_bounds__(256) void embed_k(
    const float* __restrict__ depot_xy, const float* __restrict__ node_xy,
    const float* __restrict__ node_demand,
    const float* __restrict__ wD, const float* __restrict__ bD,
    const float* __restrict__ wN, const float* __restrict__ bN,
    float* __restrict__ x)
{
  int t = blockIdx.x*256 + threadIdx.x;
  if (t >= Mtok*Ee) return;
  int e   = t & (Ee-1);
  int tok = t >> 7;
  int b   = tok / NT;
  int n   = tok - b*NT;
  float v;
  if (n == 0) {
    v = depot_xy[b*2+0]*wD[0*Ee+e] + depot_xy[b*2+1]*wD[1*Ee+e] + bD[e];
  } else {
    int nn = n - 1;
    float c0 = node_xy[(b*Nn + nn)*2 + 0];
    float c1 = node_xy[(b*Nn + nn)*2 + 1];
    float c2 = node_demand[b*Nn + nn];
    v = c0*wN[0*Ee+e] + c1*wN[1*Ee+e] + c2*wN[2*Ee+e] + bN[e];
  }
  x[(size_t)tok*Ee + e] = v;
}

// ---------------------------------------------------------------- GEMM
// C[M,N] = A[M,K] @ W[K,N]  (+bias) (relu) (+res).  N%64==0, K%16==0.
// Software-pipelined: next K-tile's global loads issued before compute.
__global__ __launch_bounds__(256) void gemm_k(
    const float* __restrict__ A, const float* __restrict__ W,
    const float* __restrict__ bias, const float* __restrict__ res,
    float* __restrict__ C, int M, int N, int K, int relu)
{
  __shared__ __align__(16) float As[16][64];
  __shared__ __align__(16) float Bs[16][64];
  int tid = threadIdx.x;
  int tx = tid & 15, ty = tid >> 4;
  int m0 = blockIdx.x * 64, n0 = blockIdx.y * 64;
  float acc[4][4];
  #pragma unroll
  for (int i=0;i<4;i++)
    #pragma unroll
    for (int j=0;j<4;j++) acc[i][j] = 0.f;

  int ar = tid >> 2;          // 0..63  A row in tile
  int ak = (tid & 3) << 2;    // 0,4,8,12
  int br = tid >> 4;          // 0..15  W row in tile
  int bc = (tid & 15) << 2;   // 0..60

  const float* Ap = A + (size_t)(m0 + ar)*K + ak;
  const float* Wp = W + (size_t)br*N + n0 + bc;
  bool aok = (m0 + ar) < M;

  float4 av = aok ? *(const float4*)(Ap) : make_float4(0.f,0.f,0.f,0.f);
  float4 wv = *(const float4*)(Wp);

  for (int k0 = 0; k0 < K; k0 += 16) {
    As[ak+0][ar] = av.x; As[ak+1][ar] = av.y; As[ak+2][ar] = av.z; As[ak+3][ar] = av.w;
    *(float4*)(&Bs[br][bc]) = wv;
    __syncthreads();
    if (k0 + 16 < K) {
      av = aok ? *(const float4*)(Ap + k0 + 16) : make_float4(0.f,0.f,0.f,0.f);
      wv = *(const float4*)(Wp + (size_t)(k0 + 16)*N);
    }
    #pragma unroll
    for (int k=0;k<16;k++){
      float4 a4 = *(const float4*)(&As[k][ty*4]);
      float4 b4 = *(const float4*)(&Bs[k][tx*4]);
      float avv[4] = {a4.x,a4.y,a4.z,a4.w};
      float bvv[4] = {b4.x,b4.y,b4.z,b4.w};
      #pragma unroll
      for (int i=0;i<4;i++)
        #pragma unroll
        for (int j=0;j<4;j++)
          acc[i][j] = fmaf(avv[i], bvv[j], acc[i][j]);
    }
    __syncthreads();
  }

  float4 bv = make_float4(0.f,0.f,0.f,0.f);
  if (bias) bv = *(const float4*)(bias + n0 + tx*4);
  #pragma unroll
  for (int i=0;i<4;i++){
    int row = m0 + ty*4 + i;
    if (row >= M) continue;
    float4 o;
    o.x = acc[i][0] + bv.x; o.y = acc[i][1] + bv.y;
    o.z = acc[i][2] + bv.z; o.w = acc[i][3] + bv.w;
    if (relu){ o.x=fmaxf(o.x,0.f); o.y=fmaxf(o.y,0.f); o.z=fmaxf(o.z,0.f); o.w=fmaxf(o.w,0.f); }
    if (res){
      float4 rv = *(const float4*)(res + (size_t)row*N + n0 + tx*4);
      o.x += rv.x; o.y += rv.y; o.z += rv.z; o.w += rv.w;
    }
    *(float4*)(C + (size_t)row*N + n0 + tx*4) = o;
  }
}

// ---------------------------------------------------------------- attention
__device__ __forceinline__ float dot4(float4 a, float4 b){
  return fmaf(a.x,b.x, fmaf(a.y,b.y, fmaf(a.z,b.z, a.w*b.w)));
}

// encoder self-attention: one (b,h,chunk) per block, one query per thread.
// K/V tiles double-buffered in LDS; j-loop reads are same-address broadcasts.
__global__ __launch_bounds__(256) void attn_enc_k(
    const float* __restrict__ Q, const float* __restrict__ Kv,
    const float* __restrict__ Vv, float* __restrict__ O)
{
  int blk = blockIdx.x;            // ((b*H)+h)*2 + c
  int c  = blk & 1;
  int bh = blk >> 1;
  int h  = bh & (Hh-1);
  int b  = bh >> 3;
  int p  = c*256 + (int)threadIdx.x;
  const size_t base = ((size_t)b*NT)*Ee + h*Dd;

  __shared__ __align__(16) float4 Ks[2][TJ][4];
  __shared__ __align__(16) float4 Vs[2][TJ][4];

  int tid = threadIdx.x;
  int row = (tid >> 2) & 31;        // 0..31
  int lc  = tid & 3;                // float4 quad within row
  bool isV = tid >= 128;
  const float* srcKV = isV ? Vv : Kv;

  float4 q0,q1,q2,q3;
  if (p < NT) {
    const float4* qp = (const float4*)(Q + base + (size_t)p*Ee);
    q0=qp[0]; q1=qp[1]; q2=qp[2]; q3=qp[3];
  } else {
    q0=q1=q2=q3=make_float4(0,0,0,0);
  }

  // load tile 0
  {
    int jj = row;
    if (jj < NT) {
      float4 v = *((const float4*)(srcKV + base + (size_t)jj*Ee) + lc);
      if (isV) Vs[0][row][lc] = v; else Ks[0][row][lc] = v;
    }
  }
  __syncthreads();

  float m = -1e30f, l = 0.f;
  float4 o0=make_float4(0,0,0,0), o1=o0, o2=o0, o3=o0;
  const int ntiles = (NT + TJ - 1)/TJ;   // 16
  int buf = 0;

  for (int t = 0; t < ntiles; ++t) {
    int j0 = t*TJ;
    // prefetch next tile into the other buffer
    if (t+1 < ntiles) {
      int jj = j0 + TJ + row;
      if (jj < NT) {
        float4 v = *((const float4*)(srcKV + base + (size_t)jj*Ee) + lc);
        if (isV) Vs[buf^1][row][lc] = v; else Ks[buf^1][row][lc] = v;
      }
    }
    int jend = NT - j0; if (jend > TJ) jend = TJ;

    if (p < NT) {
      if (jend == TJ) {
        #pragma unroll 8
        for (int jj=0;jj<TJ;jj++){
          const float4* kr = &Ks[buf][jj][0];
          float s = (dot4(q0,kr[0])+dot4(q1,kr[1])) + (dot4(q2,kr[2])+dot4(q3,kr[3]));
          s *= 0.25f;
          float mn = fmaxf(m, s);
          float cf = __expf(m - mn);
          float w  = __expf(s - mn);
          l = l*cf + w;
          const float4* vr = &Vs[buf][jj][0];
          float4 v0=vr[0],v1=vr[1],v2=vr[2],v3=vr[3];
          o0.x=fmaf(w,v0.x,o0.x*cf); o0.y=fmaf(w,v0.y,o0.y*cf); o0.z=fmaf(w,v0.z,o0.z*cf); o0.w=fmaf(w,v0.w,o0.w*cf);
          o1.x=fmaf(w,v1.x,o1.x*cf); o1.y=fmaf(w,v1.y,o1.y*cf); o1.z=fmaf(w,v1.z,o1.z*cf); o1.w=fmaf(w,v1.w,o1.w*cf);
          o2.x=fmaf(w,v2.x,o2.x*cf); o2.y=fmaf(w,v2.y,o2.y*cf); o2.z=fmaf(w,v2.z,o2.z*cf); o2.w=fmaf(w,v2.w,o2.w*cf);
          o3.x=fmaf(w,v3.x,o3.x*cf); o3.y=fmaf(w,v3.y,o3.y*cf); o3.z=fmaf(w,v3.z,o3.z*cf); o3.w=fmaf(w,v3.w,o3.w*cf);
          m = mn;
        }
      } else {
        for (int jj=0;jj<jend;jj++){
          const float4* kr = &Ks[buf][jj][0];
          float s = (dot4(q0,kr[0])+dot4(q1,kr[1])) + (dot4(q2,kr[2])+dot4(q3,kr[3]));
          s *= 0.25f;
          float mn = fmaxf(m, s);
          float cf = __expf(m - mn);
          float w  = __expf(s - mn);
          l = l*cf + w;
          const float4* vr = &Vs[buf][jj][0];
          float4 v0=vr[0],v1=vr[1],v2=vr[2],v3=vr[3];
          o0.x=fmaf(w,v0.x,o0.x*cf); o0.y=fmaf(w,v0.y,o0.y*cf); o0.z=fmaf(w,v0.z,o0.z*cf); o0.w=fmaf(w,v0.w,o0.w*cf);
          o1.x=fmaf(w,v1.x,o1.x*cf); o1.y=fmaf(w,v1.y,o1.y*cf); o1.z=fmaf(w,v1.z,o1.z*cf); o1.w=fmaf(w,v1.w,o1.w*cf);
          o2.x=fmaf(w,v2.x,o2.x*cf); o2.y=fmaf(w,v2.y,o2.y*cf); o2.z=fmaf(w,v2.z,o2.z*cf); o2.w=fmaf(w,v2.w,o2.w*cf);
          o3.x=fmaf(w,v3.x,o3.x*cf); o3.y=fmaf(w,v3.y,o3.y*cf); o3.z=fmaf(w,v3.z,o3.z*cf); o3.w=fmaf(w,v3.w,o3.w*cf);
          m = mn;
        }
      }
    }
    __syncthreads();
    buf ^= 1;
  }

  if (p < NT) {
    float inv = 1.0f/l;
    float4* op = (float4*)(O + base + (size_t)p*Ee);
    op[0] = make_float4(o0.x*inv,o0.y*inv,o0.z*inv,o0.w*inv);
    op[1] = make_float4(o1.x*inv,o1.y*inv,o1.z*inv,o1.w*inv);
    op[2] = make_float4(o2.x*inv,o2.y*inv,o2.z*inv,o2.w*inv);
    op[3] = make_float4(o3.x*inv,o3.y*inv,o3.z*inv,o3.w*inv);
  }
}

// decoder cross-attention: one block per (b,p), 128 threads = (head h, dim i).
__global__ __launch_bounds__(128) void attn_dec_k(
    const float* __restrict__ Q, const float* __restrict__ Kv,
    const float* __restrict__ Vv, const float* __restrict__ mask,
    float* __restrict__ O)
{
  int r = blockIdx.x;              // b*Pp + p
  int b = r / Pp;
  int t = threadIdx.x;             // h*16 + i
  float qv = Q[(size_t)r*Ee + t];
  const float* kb = Kv + ((size_t)b*NT)*Ee;
  const float* vb = Vv + ((size_t)b*NT)*Ee;
  const float* mrow = mask + (size_t)r*NT;
  float m = -1e30f, l = 0.f, o = 0.f;
  for (int j=0;j<NT;++j){
    float kv = kb[(size_t)j*Ee + t];
    float s = qv * kv;
    s += __shfl_xor(s, 1, 16);
    s += __shfl_xor(s, 2, 16);
    s += __shfl_xor(s, 4, 16);
    s += __shfl_xor(s, 8, 16);
    s = s*0.25f + mrow[j];
    float mn = fmaxf(m, s);
    float cf = __expf(m - mn);
    float w  = __expf(s - mn);
    l = l*cf + w;
    o = fmaf(w, vb[(size_t)j*Ee + t], o*cf);
    m = mn;
  }
  O[(size_t)r*Ee + t] = o / l;
}

// ---------------------------------------------------------------- decoder small ops
__global__ __launch_bounds__(256) void gather_k(
    const float* __restrict__ x, const int* __restrict__ cur, float* __restrict__ encl)
{
  int t = blockIdx.x*256 + threadIdx.x;
  if (t >= PR*Ee) return;
  int e = t & (Ee-1);
  int r = t >> 7;            // b*P + p
  int b = r / Pp;
  int node = cur[r];
  encl[(size_t)r*Ee + e] = x[((size_t)(b*NT + node))*Ee + e];
}

// q = concat(encl, load) @ Wq[129,128]
__global__ __launch_bounds__(128) void decq_k(
    const float* __restrict__ encl, const float* __restrict__ loadv,
    const float* __restrict__ Wq, float* __restrict__ q)
{
  __shared__ float row[Ee];
  int r = blockIdx.x, e = threadIdx.x;
  row[e] = encl[(size_t)r*Ee + e];
  __syncthreads();
  float acc = 0.f;
  #pragma unroll 4
  for (int k=0;k<Ee;k++) acc = fmaf(row[k], Wq[k*128 + e], acc);
  acc = fmaf(loadv[r], Wq[Ee*128 + e], acc);
  q[(size_t)r*128 + e] = acc;
}

// mh = att@W + b + encl + load*capw
__global__ __launch_bounds__(128) void dec_comb_k(
    const float* __restrict__ att, const float* __restrict__ W,
    const float* __restrict__ bias, const float* __restrict__ encl,
    const float* __restrict__ loadv, const float* __restrict__ capw,
    float* __restrict__ mh)
{
  __shared__ float row[Ee];
  int r = blockIdx.x, e = threadIdx.x;
  row[e] = att[(size_t)r*Ee + e];
  __syncthreads();
  float acc = 0.f;
  #pragma unroll 4
  for (int k=0;k<Ee;k++) acc = fmaf(row[k], W[k*Ee + e], acc);
  mh[(size_t)r*Ee + e] = acc + bias[e] + encl[(size_t)r*Ee + e] + loadv[r]*capw[e];
}

// score[b,p,n] = dot(qref[b,p], x[b,n]) / sqrt(E)
__global__ __launch_bounds__(128) void score_k(
    const float* __restrict__ qref, const float* __restrict__ x, float* __restrict__ score)
{
  __shared__ float q[Ee];
  int r = blockIdx.x;
  int b = r / Pp;
  q[threadIdx.x] = qref[(size_t)r*Ee + threadIdx.x];
  __syncthreads();
  for (int n = threadIdx.x; n < NT; n += 128){
    const float4* xr = (const float4*)(x + ((size_t)(b*NT + n))*Ee);
    float acc = 0.f;
    #pragma unroll
    for (int k=0;k<Ee/4;k++){
      float4 xv = xr[k];
      const float* qq = &q[k*4];
      acc = fmaf(qq[0],xv.x, fmaf(qq[1],xv.y, fmaf(qq[2],xv.z, fmaf(qq[3],xv.w, acc))));
    }
    score[(size_t)r*NT + n] = acc * 0.08838834764831845f;  // 1/sqrt(128)
  }
}

// ---------------------------------------------------------------- threefry noise
// jax >= 0.4.30 default: jax_threefry_partitionable=True.
// Per element i: threefry2x32(key=(0,42), x=(hi(i), lo(i))=(0, i)), bits = out0 ^ out1.
__device__ __forceinline__ unsigned rotl32(unsigned x, int r){ return (x<<r)|(x>>(32-r)); }

__device__ float tf_normal(unsigned idx)
{
  unsigned x0 = 0u;      // counts >> 32
  unsigned x1 = idx;     // counts & 0xffffffff
  const unsigned ks[3] = {0u, 42u, 0u ^ 42u ^ 0x1BD11BDAu};
  x0 += ks[0]; x1 += ks[1];
  const int rotA[4] = {13,15,26,6};
  const int rotB[4] = {17,29,16,24};
  #pragma unroll
  for (int i=0;i<5;i++){
    #pragma unroll
    for (int q=0;q<4;q++){
      int rr = (i&1) ? rotB[q] : rotA[q];
      x0 += x1; x1 = rotl32(x1, rr); x1 ^= x0;
    }
    x0 += ks[(i+1)%3];
    x1 += ks[(i+2)%3] + (unsigned)(i+1);
  }
  unsigned bits = x0 ^ x1;   // partitionable 32-bit draw
  // uniform in [lo, 1): jax _uniform  (f32, bit-matching jax)
  float f = __uint_as_float((bits >> 9) | 0x3f800000u) - 1.0f;
  const float lo = -0.99999994f;               // nextafter(-1,0) f32
  float u = f * 2.0f + lo;                     // (hi-lo) rounds to 2.0f in f32
  u = fmaxf(lo, u);
  // erfinv (XLA f32)
  float w = -log1pf(-u*u);
  float p;
  if (w < 5.0f) {
    w -= 2.5f;
    p = 2.81022636e-08f;
    p = fmaf(p, w, 3.43273939e-07f);
    p = fmaf(p, w, -3.5233877e-06f);
    p = fmaf(p, w, -4.39150654e-06f);
    p = fmaf(p, w, 0.00021858087f);
    p = fmaf(p, w, -0.00125372503f);
    p = fmaf(p, w, -0.00417768164f);
    p = fmaf(p, w, 0.246640727f);
    p = fmaf(p, w, 1.50140941f);
  } else {
    w = sqrtf(w) - 3.0f;
    p = -0.000200214257f;
    p = fmaf(p, w, 0.000100950558f);
    p = fmaf(p, w, 0.00134934322f);
    p = fmaf(p, w, -0.00367342844f);
    p = fmaf(p, w, 0.00573950773f);
    p = fmaf(p, w, -0.0076224613f);
    p = fmaf(p, w, 0.00943887047f);
    p = fmaf(p, w, 1.00167406f);
    p = fmaf(p, w, 2.83297682f);
  }
  return 1.4142135623730951f * (p * u);   // sqrt(2) * erfinv(u)
}

// ---------------------------------------------------------------- finalize (f32)
__global__ __launch_bounds__(512) void final_k(
    const float* __restrict__ score, const float* __restrict__ cur_dist,
    const float* __restrict__ ninf, float* __restrict__ out)
{
  __shared__ float red[512];
  const float NM = (float)(50.0/501.0);
  const float C1 = (float)(1.0 - 50.0/501.0);
  int r = blockIdx.x;
  int t = threadIdx.x;
  float cd = 0.f, dmn = 1e30f, dmx = -1e30f;
  if (t < NT) { cd = cur_dist[(size_t)r*NT + t]; dmn = cd; dmx = cd; }
  red[t] = dmn; __syncthreads();
  for (int s=256;s>0;s>>=1){ if (t<s) red[t]=fminf(red[t],red[t+s]); __syncthreads(); }
  float dmin = red[0]; __syncthreads();
  red[t] = dmx; __syncthreads();
  for (int s=256;s>0;s>>=1){ if (t<s) red[t]=fmaxf(red[t],red[t+s]); __syncthreads(); }
  float dmax = red[0]; __syncthreads();

  float sval = -1e30f;
  if (t < NT) {
    float nd = (cd - dmin) / (dmax - dmin + 1e-6f);
    float z  = tf_normal((unsigned)r*501u + (unsigned)t);
    float s  = score[(size_t)r*NT + t] - C1*logf(nd + 1e-6f) + (z*0.2f + 0.5f)*NM;
    sval = 10.0f*tanhf(s) + ninf[(size_t)r*NT + t];
  }
  red[t] = sval; __syncthreads();
  for (int s=256;s>0;s>>=1){ if (t<s) red[t]=fmaxf(red[t],red[t+s]); __syncthreads(); }
  float smax = red[0]; __syncthreads();
  float e = (t < NT) ? expf(sval - smax) : 0.f;
  red[t] = e; __syncthreads();
  for (int s=256;s>0;s>>=1){ if (t<s) red[t]+=red[t+s]; __syncthreads(); }
  float ssum = red[0];
  if (t < NT) out[(size_t)r*NT + t] = e / ssum;
}

// ---------------------------------------------------------------- launch
extern "C" void kernel_launch(void* const* d_in, const int* in_sizes, int n_in,
                              void* d_out, int out_size, void* d_ws, size_t ws_size,
                              hipStream_t stream)
{
  (void)in_sizes; (void)n_in; (void)out_size; (void)ws_size;
  const float* depot_xy    = (const float*)d_in[0];
  const float* node_xy     = (const float*)d_in[1];
  const float* node_demand = (const float*)d_in[2];
  const float* loadv       = (const float*)d_in[3];
  const float* cur_dist    = (const float*)d_in[4];
  const float* ninf        = (const float*)d_in[5];
  const int*   cur_node    = (const int*)d_in[6];
  const float* emb_depot_w = (const float*)d_in[7];
  const float* emb_depot_b = (const float*)d_in[8];
  const float* emb_node_w  = (const float*)d_in[9];
  const float* emb_node_b  = (const float*)d_in[10];
  const float* enc_wq      = (const float*)d_in[11];
  const float* enc_wk      = (const float*)d_in[12];
  const float* enc_wv      = (const float*)d_in[13];
  const float* enc_comb_w  = (const float*)d_in[14];
  const float* enc_comb_b  = (const float*)d_in[15];
  const float* enc_ff1_w   = (const float*)d_in[16];
  const float* enc_ff1_b   = (const float*)d_in[17];
  const float* enc_ff2_w   = (const float*)d_in[18];
  const float* enc_ff2_b   = (const float*)d_in[19];
  const float* dec_wq_last = (const float*)d_in[20];
  const float* dec_wk      = (const float*)d_in[21];
  const float* dec_wv      = (const float*)d_in[22];
  const float* dec_comb_w  = (const float*)d_in[23];
  const float* dec_comb_b  = (const float*)d_in[24];
  const float* dec_cap_w   = (const float*)d_in[25];
  const float* dec_ff1_w   = (const float*)d_in[26];
  const float* dec_ff1_b   = (const float*)d_in[27];
  const float* dec_ff2_w   = (const float*)d_in[28];
  const float* dec_ff2_b   = (const float*)d_in[29];

  float* ws = (float*)d_ws;
  const size_t SZ = (size_t)Mtok*Ee;   // 1,026,048
  float* xb   = ws + 0*SZ;
  float* qb   = ws + 1*SZ;
  float* kb   = ws + 2*SZ;
  float* vb   = ws + 3*SZ;
  float* atb  = ws + 4*SZ;
  float* o1b  = ws + 5*SZ;
  float* ffb  = ws + 6*SZ;             // Mtok*Ff floats
  // decoder reuse
  float* dk    = qb;
  float* dv    = kb;
  float* encl  = vb;
  float* qdec  = vb + 204800;
  float* attd  = vb + 409600;
  float* mhb   = vb + 614400;
  float* qrefb = atb;
  float* ffh2  = ffb;
  float* scoreb= o1b;

  embed_k<<<(Mtok*Ee + 255)/256, 256, 0, stream>>>(
      depot_xy, node_xy, node_demand, emb_depot_w, emb_depot_b,
      emb_node_w, emb_node_b, xb);

  dim3 g128((Mtok + 63)/64, Ee/64);
  dim3 gff ((Mtok + 63)/64, Ff/64);
  for (int l = 0; l < Ll; ++l) {
    gemm_k<<<g128, 256, 0, stream>>>(xb, enc_wq + (size_t)l*Ee*Ee, nullptr, nullptr, qb, Mtok, Ee, Ee, 0);
    gemm_k<<<g128, 256, 0, stream>>>(xb, enc_wk + (size_t)l*Ee*Ee, nullptr, nullptr, kb, Mtok, Ee, Ee, 0);
    gemm_k<<<g128, 256, 0, stream>>>(xb, enc_wv + (size_t)l*Ee*Ee, nullptr, nullptr, vb, Mtok, Ee, Ee, 0);
    attn_enc_k<<<Bb*Hh*2, 256, 0, stream>>>(qb, kb, vb, atb);
    gemm_k<<<g128, 256, 0, stream>>>(atb, enc_comb_w + (size_t)l*Ee*Ee, enc_comb_b + l*Ee, xb, o1b, Mtok, Ee, Ee, 0);
    gemm_k<<<gff, 256, 0, stream>>>(o1b, enc_ff1_w + (size_t)l*Ee*Ff, enc_ff1_b + l*Ff, nullptr, ffb, Mtok, Ff, Ee, 1);
    gemm_k<<<g128, 256, 0, stream>>>(ffb, enc_ff2_w + (size_t)l*Ff*Ee, enc_ff2_b + l*Ee, o1b, xb, Mtok, Ee, Ff, 0);
  }

  // decoder
  gemm_k<<<g128, 256, 0, stream>>>(xb, dec_wk, nullptr, nullptr, dk, Mtok, Ee, Ee, 0);
  gemm_k<<<g128, 256, 0, stream>>>(xb, dec_wv, nullptr, nullptr, dv, Mtok, Ee, Ee, 0);
  gather_k<<<(PR*Ee + 255)/256, 256, 0, stream>>>(xb, cur_node, encl);
  decq_k<<<PR, 128, 0, stream>>>(encl, loadv, dec_wq_last, qdec);
  attn_dec_k<<<PR, 128, 0, stream>>>(qdec, dk, dv, ninf, attd);
  dec_comb_k<<<PR, 128, 0, stream>>>(attd, dec_comb_w, dec_comb_b, encl, loadv, dec_cap_w, mhb);
  dim3 gd1((PR + 63)/64, Ff/64);
  gemm_k<<<gd1, 256, 0, stream>>>(mhb, dec_ff1_w, dec_ff1_b, nullptr, ffh2, PR, Ff, Ee, 1);
  dim3 gd2((PR + 63)/64, Ee/64);
  gemm_k<<<gd2, 256, 0, stream>>>(ffh2, dec_ff2_w, dec_ff2_b, mhb, qrefb, PR, Ee, Ff, 0);
  score_k<<<PR, 128, 0, stream>>>(qrefb, xb, scoreb);
  final_k<<<PR, 512, 0, stream>>>(scoreb, cur_dist, ninf, (float*)d_out);
}